// Round 10
// baseline (326.430 us; speedup 1.0000x reference)
//
#include <hip/hip_runtime.h>
#include <hip/hip_bf16.h>

typedef _Float16 f16;
typedef _Float16 f16x4 __attribute__((ext_vector_type(4)));
typedef _Float16 f16x8 __attribute__((ext_vector_type(8)));
typedef float f32x4 __attribute__((ext_vector_type(4)));

constexpr int BATCH = 4, C = 512, CQ = 128, N = 4096;
constexpr int FKD = 256; // f(128) + k(128) channels, stacked

// workspace layout (bytes)
constexpr size_t WS_XT   = 0;                                      // f16 [B][N][C]   16 MB
constexpr size_t WS_FK   = WS_XT   + (size_t)BATCH * N * C * 2;    // f16 [B][N][256]  8 MB
constexpr size_t WS_V    = WS_FK   + (size_t)BATCH * N * FKD * 2;  // f16 [B][C][N]   16 MB
constexpr size_t WS_WCAT = WS_V    + (size_t)BATCH * C * N * 2;    // f16 [256][512]
constexpr size_t WS_WL   = WS_WCAT + (size_t)FKD * C * 2;          // f16 [512][512]
constexpr size_t WS_BC   = WS_WL   + (size_t)C * C * 2;            // f32 [256]

#define AS1(p) ((const __attribute__((address_space(1))) void*)(p))
#define AS3(p) ((__attribute__((address_space(3))) void*)(p))

// ---------------------------------------------------------------- weights->fp16
__global__ void prep_weights(const float* __restrict__ Wf_w, const float* __restrict__ Wf_b,
                             const float* __restrict__ Wh_w, const float* __restrict__ Wh_b,
                             const float* __restrict__ Wl_w,
                             f16* __restrict__ wcat, f16* __restrict__ wl, float* __restrict__ bcat) {
    int i = blockIdx.x * 256 + threadIdx.x;                 // grid covers C*C
    if (i < FKD * C) {
        int o = i >> 9, c = i & 511;
        float v = (o < CQ) ? Wf_w[o * C + c] : Wh_w[(o - CQ) * C + c];
        wcat[i] = (f16)v;
    }
    if (i < C * C) wl[i] = (f16)Wl_w[i];
    if (i < FKD) bcat[i] = (i < CQ) ? Wf_b[i] : Wh_b[i - CQ];
}

// ---------------------------------------------------------------- x (B,C,N) f32 -> xT (B,N,C) f16
__global__ void transpose_x(const float* __restrict__ x, f16* __restrict__ xt) {
    __shared__ float tile[64][65];
    int gid = blockIdx.x;
    int b = gid >> 9, rem = gid & 511;
    int c0 = (rem >> 6) * 64, n0 = (rem & 63) * 64;
    int t = threadIdx.x;
    int tn = t & 63, tg = t >> 6;
    const float* xp = x + (size_t)b * C * N + (size_t)c0 * N + n0;
#pragma unroll
    for (int r = 0; r < 16; ++r) {
        int cl = tg + r * 4;
        tile[cl][tn] = xp[(size_t)cl * N + tn];
    }
    __syncthreads();
    f16* xo = xt + (size_t)b * N * C + (size_t)n0 * C + c0;
#pragma unroll
    for (int r = 0; r < 16; ++r) {
        int nl = tg + r * 4;
        xo[(size_t)nl * C + tn] = (f16)tile[tn][nl];
    }
}

// ---------------------------------------------------------------- FK projection (64n x 64o per wave)
__global__ void __launch_bounds__(256) proj_fk(const f16* __restrict__ xt, const f16* __restrict__ wcat,
                                               const float* __restrict__ bcat, f16* __restrict__ fk) {
    int wid = blockIdx.x * 4 + (threadIdx.x >> 6);   // 1024 waves: b(2) nt(6) ot(2)
    int lane = threadIdx.x & 63;
    int li = lane & 15, lg = lane >> 4;
    int b  = wid >> 8;
    int nt = (wid >> 2) & 63;
    int ot = wid & 3;
    int n0 = nt * 64, o0 = ot * 64;
    const f16* ap = xt + (size_t)(b * N + n0 + li) * C + lg * 8;
    const f16* bp = wcat + (size_t)(o0 + li) * C + lg * 8;
    f32x4 acc[4][4] = {};
    for (int ks = 0; ks < 16; ++ks) {
        f16x8 a4[4], b4[4];
#pragma unroll
        for (int t = 0; t < 4; ++t) a4[t] = *(const f16x8*)(ap + (size_t)(t * 16) * C + ks * 32);
#pragma unroll
        for (int t = 0; t < 4; ++t) b4[t] = *(const f16x8*)(bp + (size_t)(t * 16) * C + ks * 32);
#pragma unroll
        for (int tA = 0; tA < 4; ++tA)
#pragma unroll
            for (int tB = 0; tB < 4; ++tB)
                acc[tA][tB] = __builtin_amdgcn_mfma_f32_16x16x32_f16(a4[tA], b4[tB], acc[tA][tB], 0, 0, 0);
    }
#pragma unroll
    for (int tB = 0; tB < 4; ++tB) {
        int o = o0 + tB * 16 + li;
        float bias = bcat[o];
#pragma unroll
        for (int tA = 0; tA < 4; ++tA)
#pragma unroll
            for (int r = 0; r < 4; ++r) {
                int n = n0 + tA * 16 + lg * 4 + r;
                fk[(size_t)(b * N + n) * FKD + o] = (f16)(acc[tA][tB][r] + bias);
            }
    }
}

// ---------------------------------------------------------------- V projection (64c x 64n per wave)
__global__ void __launch_bounds__(256) proj_v(const f16* __restrict__ xt, const f16* __restrict__ wl,
                                              const float* __restrict__ wlb, f16* __restrict__ v) {
    int wid = blockIdx.x * 4 + (threadIdx.x >> 6);   // 2048 waves: b(2) ct(3) nt(6)
    int lane = threadIdx.x & 63;
    int li = lane & 15, lg = lane >> 4;
    int b  = wid >> 9;
    int ct = (wid >> 6) & 7;
    int nt = wid & 63;
    int c0 = ct * 64, n0 = nt * 64;
    const f16* ap = wl + (size_t)(c0 + li) * C + lg * 8;
    const f16* bp = xt + (size_t)(b * N + n0 + li) * C + lg * 8;
    f32x4 acc[4][4] = {};
    for (int ks = 0; ks < 16; ++ks) {
        f16x8 a4[4], b4[4];
#pragma unroll
        for (int t = 0; t < 4; ++t) a4[t] = *(const f16x8*)(ap + (size_t)(t * 16) * C + ks * 32);
#pragma unroll
        for (int t = 0; t < 4; ++t) b4[t] = *(const f16x8*)(bp + (size_t)(t * 16) * C + ks * 32);
#pragma unroll
        for (int tA = 0; tA < 4; ++tA)
#pragma unroll
            for (int tB = 0; tB < 4; ++tB)
                acc[tA][tB] = __builtin_amdgcn_mfma_f32_16x16x32_f16(a4[tA], b4[tB], acc[tA][tB], 0, 0, 0);
    }
#pragma unroll
    for (int tA = 0; tA < 4; ++tA)
#pragma unroll
        for (int r = 0; r < 4; ++r) {
            int c = c0 + tA * 16 + lg * 4 + r;
            float bias = wlb[c];
#pragma unroll
            for (int tB = 0; tB < 4; ++tB) {
                int n = n0 + tB * 16 + li;
                v[(size_t)(b * C + c) * N + n] = (f16)(acc[tA][tB][r] + bias);
            }
        }
}

// ---------------------------------------------------------------- flash attention + residual (v10)
// 512 blocks = b(4, XCD-pinned) x it(64q tiles) x ch(c-half). Each block: 8 waves,
// KVBLK=128, single 32KB kbuf (v9 hazard pattern), pbuf[64][128] 16KB, stats 4KB
// -> 52 KB LDS total; launch_bounds(512,2) -> 128 VGPR. 2 blocks/CU co-resident
// (4 waves/SIMD) so barrier convoys of one block overlap compute of the other.
// QK duplicated per c-half (+25% MFMA, cheapest 2x-parallelism split). Per-XCD
// working set: one batch AND one c-half of V -> ~6 MB (vs 12), L2-resident.
// Wave wv: QK j-slice [wv*16,+16); PV c-slice c0 = ch*256 + wv*32 (2 c-frags).
__global__ void __launch_bounds__(512, 2) attn(const f16* __restrict__ fk, const f16* __restrict__ v,
                                               const float* __restrict__ x, const float* __restrict__ alphap,
                                               float* __restrict__ out) {
    __shared__ __align__(16) f16 kbuf[128 * 128];      // 32 KB, single buffer
    __shared__ __align__(16) f16 pbuf[64 * 128];       // 16 KB shared P
    __shared__ float smax[8][4][16];
    __shared__ float ssum[8][4][16];

    const int tid  = threadIdx.x;
    const int wv   = tid >> 6;
    const int lane = tid & 63;
    const int li = lane & 15, lg = lane >> 4;
    const int swl = li & 7;
    // decode: XCD = v0&7 under round-robin; batch pinned per XCD-pair, c-half per XCD
    const int v0 = blockIdx.x;
    const int b  = (v0 & 7) >> 1;
    const int ch = v0 & 1;
    const int it = v0 >> 3;            // 0..63
    const int i0 = it * 64;
    const int c0 = ch * 256 + wv * 32;

    // F fragments (B operand of swapped QK): col=i, k=ck; 4 i-frags
    f16x8 fb[4][4];
#pragma unroll
    for (int f = 0; f < 4; ++f) {
        const f16* fp = fk + (size_t)(b * N + i0 + f * 16 + li) * FKD + lg * 8;
#pragma unroll
        for (int ks = 0; ks < 4; ++ks) fb[f][ks] = *(const f16x8*)(fp + ks * 32);
    }

    // K staging: wave wv stages rows [wv*16, wv*16+16), 4 gld_lds (16B/lane).
    // LDS dest linear (lane -> row lg, granule li); source granule li ^ (row&7).
    auto STAGE = [&](int tile) {
#pragma unroll
        for (int q = 0; q < 4; ++q) {
            const int row = wv * 16 + q * 4 + lg;
            const f16* gsrc = fk + (size_t)(b * N + tile * 128 + row) * FKD + CQ + (li ^ ((q * 4 + lg) & 7)) * 8;
            __builtin_amdgcn_global_load_lds(AS1(gsrc), AS3(&kbuf[(wv * 16 + q * 4) * 128]), 16, 0, 0);
        }
    };

    STAGE(0);
    const f16* vbase = v + (size_t)(b * C + c0 + li) * N + lg * 8;
    f32x4 oacc[2][4] = {};                       // [c-frag][i-frag]
    float ms[4] = {-1e30f, -1e30f, -1e30f, -1e30f};
    float ls[4] = {0.f, 0.f, 0.f, 0.f};
    __syncthreads();                             // tile 0 staged

    for (int t = 0; t < 32; ++t) {
        const int j0 = t * 128;
        // (a) QK for this wave's 16-j slice, all 4 i-frags
        f16x8 kf4[4];
#pragma unroll
        for (int ks = 0; ks < 4; ++ks)
            kf4[ks] = *(const f16x8*)(&kbuf[(wv * 16 + li) * 128 + ((ks * 4 + lg) ^ swl) * 8]);
        f32x4 s[4] = {};
        __builtin_amdgcn_s_setprio(1);
#pragma unroll
        for (int ks = 0; ks < 4; ++ks)
#pragma unroll
            for (int f = 0; f < 4; ++f)
                s[f] = __builtin_amdgcn_mfma_f32_16x16x32_f16(kf4[ks], fb[f][ks], s[f], 0, 0, 0);
        __builtin_amdgcn_s_setprio(0);
        // (b) wave-local max per query; publish
#pragma unroll
        for (int f = 0; f < 4; ++f) {
            float t0 = fmaxf(fmaxf(s[f][0], s[f][1]), fmaxf(s[f][2], s[f][3]));
            t0 = fmaxf(t0, __shfl_xor(t0, 16));
            t0 = fmaxf(t0, __shfl_xor(t0, 32));
            if (lane < 16) smax[wv][f][li] = t0;
        }
        __syncthreads();   // barA: kbuf reads done, smax visible
        // (c) stage K(t+1) into kbuf (drains at barB; read only after barB at t+1)
        if (t < 31) STAGE(t + 1);
        // (d) global max + T13 rescale
        float gm[4];
#pragma unroll
        for (int f = 0; f < 4; ++f) {
            float m0 = smax[0][f][li];
#pragma unroll
            for (int w = 1; w < 8; ++w) m0 = fmaxf(m0, smax[w][f][li]);
            gm[f] = m0;
        }
#pragma unroll
        for (int f = 0; f < 4; ++f) {
            if (!__all(gm[f] <= ms[f] + 8.0f)) {
                float mn = fmaxf(ms[f], gm[f]), sc = __expf(ms[f] - mn);
                ms[f] = mn; ls[f] *= sc;
                oacc[0][f] *= sc;
                oacc[1][f] *= sc;
            }
        }
        // (e) exp (this wave's 4 j per lane per f) + P write + partial sums
        const int jl = wv * 16 + lg * 4;
        const int gg = (jl >> 3) ^ swl;
#pragma unroll
        for (int f = 0; f < 4; ++f) {
            f16x4 pk;
            float p0 = 0.f;
#pragma unroll
            for (int r = 0; r < 4; ++r) { float p = __expf(s[f][r] - ms[f]); p0 += p; pk[r] = (f16)p; }
            *(f16x4*)(&pbuf[(f * 16 + li) * 128 + gg * 8 + (jl & 7)]) = pk;
            p0 += __shfl_xor(p0, 16);
            p0 += __shfl_xor(p0, 32);
            if (lane < 16) ssum[wv][f][li] = p0;
        }
        // V prefetch phase 0 (latency hides under barB)
        f16x8 va0[2], va1[2];
#pragma unroll
        for (int cf = 0; cf < 2; ++cf) va0[cf] = *(const f16x8*)(vbase + (size_t)(cf * 16) * N + j0);
        __syncthreads();   // barB: P + ssum visible; K(t+1) staged
        // (f) accumulate l
#pragma unroll
        for (int f = 0; f < 4; ++f) {
            float a0 = 0.f;
#pragma unroll
            for (int w = 0; w < 8; ++w) a0 += ssum[w][f][li];
            ls[f] += a0;
        }
        // (g) PV over 128 j: 4 phases, rolling 2-deep V prefetch, 8 MFMA/phase
#pragma unroll
        for (int cf = 0; cf < 2; ++cf) va1[cf] = *(const f16x8*)(vbase + (size_t)(cf * 16) * N + j0 + 32);
#pragma unroll
        for (int kf = 0; kf < 4; ++kf) {
            const int pg = (kf * 4 + lg) ^ swl;
            f16x8 pb[4];
#pragma unroll
            for (int f = 0; f < 4; ++f)
                pb[f] = *(const f16x8*)(&pbuf[(f * 16 + li) * 128 + pg * 8]);
            f16x8 vv0, vv1;
            if (kf & 1) { vv0 = va1[0]; vv1 = va1[1]; }
            else        { vv0 = va0[0]; vv1 = va0[1]; }
            if (kf < 2) {
#pragma unroll
                for (int cf = 0; cf < 2; ++cf) {
                    f16x8 nv = *(const f16x8*)(vbase + (size_t)(cf * 16) * N + j0 + (kf + 2) * 32);
                    if (kf & 1) va1[cf] = nv; else va0[cf] = nv;
                }
            }
            __builtin_amdgcn_s_setprio(1);
#pragma unroll
            for (int f = 0; f < 4; ++f) {
                oacc[0][f] = __builtin_amdgcn_mfma_f32_16x16x32_f16(vv0, pb[f], oacc[0][f], 0, 0, 0);
                oacc[1][f] = __builtin_amdgcn_mfma_f32_16x16x32_f16(vv1, pb[f], oacc[1][f], 0, 0, 0);
            }
            __builtin_amdgcn_s_setprio(0);
        }
        // pbuf reads of tile t finish before barA(t+1); writes of t+1 occur after it
    }

    // epilogue: O[c][i], i coalesced over li; + residual
    const float alpha = alphap[0];
#pragma unroll
    for (int f = 0; f < 4; ++f) {
        const float invf = alpha / ls[f];
        const float* xp = x + (size_t)(b * C + c0) * N + i0 + f * 16 + li;
        float* op = out + (size_t)(b * C + c0) * N + i0 + f * 16 + li;
#pragma unroll
        for (int cf = 0; cf < 2; ++cf)
#pragma unroll
            for (int r = 0; r < 4; ++r) {
                const int cl = cf * 16 + lg * 4 + r;
                op[(size_t)cl * N] = oacc[cf][f][r] * invf + xp[(size_t)cl * N];
            }
    }
}

extern "C" void kernel_launch(void* const* d_in, const int* in_sizes, int n_in,
                              void* d_out, int out_size, void* d_ws, size_t ws_size,
                              hipStream_t stream) {
    const float* x     = (const float*)d_in[0];
    const float* Wf_w  = (const float*)d_in[1];
    const float* Wf_b  = (const float*)d_in[2];
    const float* Wh_w  = (const float*)d_in[3];
    const float* Wh_b  = (const float*)d_in[4];
    const float* Wl_w  = (const float*)d_in[5];
    const float* Wl_b  = (const float*)d_in[6];
    const float* alpha = (const float*)d_in[7];
    char* ws = (char*)d_ws;
    f16*   xt   = (f16*)(ws + WS_XT);
    f16*   fkb  = (f16*)(ws + WS_FK);
    f16*   vb   = (f16*)(ws + WS_V);
    f16*   wcat = (f16*)(ws + WS_WCAT);
    f16*   wl   = (f16*)(ws + WS_WL);
    float* bcat = (float*)(ws + WS_BC);
    float* out  = (float*)d_out;

    prep_weights<<<dim3((C * C + 255) / 256), dim3(256), 0, stream>>>(Wf_w, Wf_b, Wh_w, Wh_b, Wl_w, wcat, wl, bcat);
    transpose_x<<<dim3(BATCH * 8 * 64), dim3(256), 0, stream>>>(x, xt);
    proj_fk<<<dim3(256), dim3(256), 0, stream>>>(xt, wcat, bcat, fkb);
    proj_v<<<dim3(512), dim3(256), 0, stream>>>(xt, wl, Wl_b, vb);
    // 4 b x 64 q-tiles x 2 c-halves = 512 blocks x 8 waves; 2 blocks/CU co-resident
    attn<<<dim3(512), dim3(512), 0, stream>>>(fkb, vb, x, alpha, out);
}

// Round 11
// 221.906 us; speedup vs baseline: 1.4710x; 1.4710x over previous
//
#include <hip/hip_runtime.h>
#include <hip/hip_bf16.h>

typedef _Float16 f16;
typedef _Float16 f16x4 __attribute__((ext_vector_type(4)));
typedef _Float16 f16x8 __attribute__((ext_vector_type(8)));
typedef float f32x4 __attribute__((ext_vector_type(4)));

constexpr int BATCH = 4, C = 512, CQ = 128, N = 4096;
constexpr int FKD = 256; // f(128) + k(128) channels, stacked

// workspace layout (bytes)
constexpr size_t WS_XT   = 0;                                      // f16 [B][N][C]   16 MB
constexpr size_t WS_FK   = WS_XT   + (size_t)BATCH * N * C * 2;    // f16 [B][N][256]  8 MB
constexpr size_t WS_V    = WS_FK   + (size_t)BATCH * N * FKD * 2;  // f16 [B][C][N]   16 MB
constexpr size_t WS_WCAT = WS_V    + (size_t)BATCH * C * N * 2;    // f16 [256][512]
constexpr size_t WS_WL   = WS_WCAT + (size_t)FKD * C * 2;          // f16 [512][512]
constexpr size_t WS_BC   = WS_WL   + (size_t)C * C * 2;            // f32 [256]

// ---------------------------------------------------------------- weights->fp16
__global__ void prep_weights(const float* __restrict__ Wf_w, const float* __restrict__ Wf_b,
                             const float* __restrict__ Wh_w, const float* __restrict__ Wh_b,
                             const float* __restrict__ Wl_w,
                             f16* __restrict__ wcat, f16* __restrict__ wl, float* __restrict__ bcat) {
    int i = blockIdx.x * 256 + threadIdx.x;                 // grid covers C*C
    if (i < FKD * C) {
        int o = i >> 9, c = i & 511;
        float v = (o < CQ) ? Wf_w[o * C + c] : Wh_w[(o - CQ) * C + c];
        wcat[i] = (f16)v;
    }
    if (i < C * C) wl[i] = (f16)Wl_w[i];
    if (i < FKD) bcat[i] = (i < CQ) ? Wf_b[i] : Wh_b[i - CQ];
}

// ---------------------------------------------------------------- x (B,C,N) f32 -> xT (B,N,C) f16
__global__ void transpose_x(const float* __restrict__ x, f16* __restrict__ xt) {
    __shared__ float tile[64][65];
    int gid = blockIdx.x;
    int b = gid >> 9, rem = gid & 511;
    int c0 = (rem >> 6) * 64, n0 = (rem & 63) * 64;
    int t = threadIdx.x;
    int tn = t & 63, tg = t >> 6;
    const float* xp = x + (size_t)b * C * N + (size_t)c0 * N + n0;
#pragma unroll
    for (int r = 0; r < 16; ++r) {
        int cl = tg + r * 4;
        tile[cl][tn] = xp[(size_t)cl * N + tn];
    }
    __syncthreads();
    f16* xo = xt + (size_t)b * N * C + (size_t)n0 * C + c0;
#pragma unroll
    for (int r = 0; r < 16; ++r) {
        int nl = tg + r * 4;
        xo[(size_t)nl * C + tn] = (f16)tile[tn][nl];
    }
}

// ---------------------------------------------------------------- FK projection (64n x 64o per wave)
__global__ void __launch_bounds__(256) proj_fk(const f16* __restrict__ xt, const f16* __restrict__ wcat,
                                               const float* __restrict__ bcat, f16* __restrict__ fk) {
    int wid = blockIdx.x * 4 + (threadIdx.x >> 6);   // 1024 waves: b(2) nt(6) ot(2)
    int lane = threadIdx.x & 63;
    int li = lane & 15, lg = lane >> 4;
    int b  = wid >> 8;
    int nt = (wid >> 2) & 63;
    int ot = wid & 3;
    int n0 = nt * 64, o0 = ot * 64;
    const f16* ap = xt + (size_t)(b * N + n0 + li) * C + lg * 8;
    const f16* bp = wcat + (size_t)(o0 + li) * C + lg * 8;
    f32x4 acc[4][4] = {};
    for (int ks = 0; ks < 16; ++ks) {
        f16x8 a4[4], b4[4];
#pragma unroll
        for (int t = 0; t < 4; ++t) a4[t] = *(const f16x8*)(ap + (size_t)(t * 16) * C + ks * 32);
#pragma unroll
        for (int t = 0; t < 4; ++t) b4[t] = *(const f16x8*)(bp + (size_t)(t * 16) * C + ks * 32);
#pragma unroll
        for (int tA = 0; tA < 4; ++tA)
#pragma unroll
            for (int tB = 0; tB < 4; ++tB)
                acc[tA][tB] = __builtin_amdgcn_mfma_f32_16x16x32_f16(a4[tA], b4[tB], acc[tA][tB], 0, 0, 0);
    }
#pragma unroll
    for (int tB = 0; tB < 4; ++tB) {
        int o = o0 + tB * 16 + li;
        float bias = bcat[o];
#pragma unroll
        for (int tA = 0; tA < 4; ++tA)
#pragma unroll
            for (int r = 0; r < 4; ++r) {
                int n = n0 + tA * 16 + lg * 4 + r;
                fk[(size_t)(b * N + n) * FKD + o] = (f16)(acc[tA][tB][r] + bias);
            }
    }
}

// ---------------------------------------------------------------- V projection (64c x 64n per wave)
__global__ void __launch_bounds__(256) proj_v(const f16* __restrict__ xt, const f16* __restrict__ wl,
                                              const float* __restrict__ wlb, f16* __restrict__ v) {
    int wid = blockIdx.x * 4 + (threadIdx.x >> 6);   // 2048 waves: b(2) ct(3) nt(6)
    int lane = threadIdx.x & 63;
    int li = lane & 15, lg = lane >> 4;
    int b  = wid >> 9;
    int ct = (wid >> 6) & 7;
    int nt = wid & 63;
    int c0 = ct * 64, n0 = nt * 64;
    const f16* ap = wl + (size_t)(c0 + li) * C + lg * 8;
    const f16* bp = xt + (size_t)(b * N + n0 + li) * C + lg * 8;
    f32x4 acc[4][4] = {};
    for (int ks = 0; ks < 16; ++ks) {
        f16x8 a4[4], b4[4];
#pragma unroll
        for (int t = 0; t < 4; ++t) a4[t] = *(const f16x8*)(ap + (size_t)(t * 16) * C + ks * 32);
#pragma unroll
        for (int t = 0; t < 4; ++t) b4[t] = *(const f16x8*)(bp + (size_t)(t * 16) * C + ks * 32);
#pragma unroll
        for (int tA = 0; tA < 4; ++tA)
#pragma unroll
            for (int tB = 0; tB < 4; ++tB)
                acc[tA][tB] = __builtin_amdgcn_mfma_f32_16x16x32_f16(a4[tA], b4[tB], acc[tA][tB], 0, 0, 0);
    }
#pragma unroll
    for (int tA = 0; tA < 4; ++tA)
#pragma unroll
        for (int r = 0; r < 4; ++r) {
            int c = c0 + tA * 16 + lg * 4 + r;
            float bias = wlb[c];
#pragma unroll
            for (int tB = 0; tB < 4; ++tB) {
                int n = n0 + tB * 16 + li;
                v[(size_t)(b * C + c) * N + n] = (f16)(acc[tA][tB][r] + bias);
            }
        }
}

// ---------------------------------------------------------------- flash attention + residual (v4 verbatim)
// Champion schedule (Round 4, 167 us): 8 waves, 64q tile, KVBLK=128, reg-staged
// double-buffered kbuf, shared-stats softmax, 2 barriers/iter, rolling V prefetch.
// 256 blocks XCD-pinned (one batch per XCD -> L2-resident K/V).
__global__ void __launch_bounds__(512, 2) attn(const f16* __restrict__ fk, const f16* __restrict__ v,
                                               const float* __restrict__ x, const float* __restrict__ alphap,
                                               float* __restrict__ out) {
    __shared__ __align__(16) f16 kbuf[2][128 * 128];   // 64 KB K tile, double-buffered
    __shared__ __align__(16) f16 pbuf[64 * 128];       // 16 KB shared P
    __shared__ float smax[8][4][16];
    __shared__ float ssum[8][4][16];

    const int tid  = threadIdx.x;
    const int wv   = tid >> 6;
    const int lane = tid & 63;
    const int li = lane & 15, lg = lane >> 4;
    const int swl = li & 7;
    // XCD-pinning: under blk%8 round-robin, each XCD sees a single batch
    const int v0 = blockIdx.x;
    const int b  = (v0 & 7) >> 1;
    const int it = ((v0 & 1) << 5) | (v0 >> 3);
    const int i0 = it * 64;
    const int c0 = wv * 64;

    // F fragments (B operand of swapped QK): col=i, k=ck; 4 i-frags
    f16x8 fb[4][4];
#pragma unroll
    for (int f = 0; f < 4; ++f) {
        const f16* fp = fk + (size_t)(b * N + i0 + f * 16 + li) * FKD + lg * 8;
#pragma unroll
        for (int ks = 0; ks < 4; ++ks) fb[f][ks] = *(const f16x8*)(fp + ks * 32);
    }

    // staging geometry: 512 thr x 64B = 32KB tile; row = tid>>2, 4 granules each
    const int sr  = tid >> 2;
    const int sg  = (tid & 3) * 4;
    const int ssw = sr & 7;
    {   // prologue: stage tile 0 -> kbuf[0]
        const f16* src = fk + (size_t)(b * N + sr) * FKD + CQ + (tid & 3) * 32;
#pragma unroll
        for (int k = 0; k < 4; ++k) {
            f16x8 vv = *(const f16x8*)(src + k * 8);
            *(f16x8*)(&kbuf[0][sr * 128 + ((sg + k) ^ ssw) * 8]) = vv;
        }
    }

    const f16* vbase = v + (size_t)(b * C + c0 + li) * N + lg * 8;
    f32x4 oacc[4][4] = {};                       // [c-frag][i-frag]
    float ms[4] = {-1e30f, -1e30f, -1e30f, -1e30f};
    float ls[4] = {0.f, 0.f, 0.f, 0.f};
    __syncthreads();

    for (int t = 0; t < 32; ++t) {
        const f16* kc = &kbuf[t & 1][0];
        f16*       kn = &kbuf[(t + 1) & 1][0];
        const int j0 = t * 128;
        // (a) issue next K-tile global loads early (T14 issue-early/write-late)
        const int jn = (t < 31) ? (t + 1) * 128 : 0;
        const f16* ssrc = fk + (size_t)(b * N + jn + sr) * FKD + CQ + (tid & 3) * 32;
        f16x8 stg[4];
#pragma unroll
        for (int k = 0; k < 4; ++k) stg[k] = *(const f16x8*)(ssrc + k * 8);

        // (b) QK for this wave's 16-j slice, all 4 i-frags
        f16x8 kf4[4];
#pragma unroll
        for (int ks = 0; ks < 4; ++ks)
            kf4[ks] = *(const f16x8*)(&kc[(wv * 16 + li) * 128 + ((ks * 4 + lg) ^ swl) * 8]);
        f32x4 s[4] = {};
        __builtin_amdgcn_s_setprio(1);
#pragma unroll
        for (int ks = 0; ks < 4; ++ks)
#pragma unroll
            for (int f = 0; f < 4; ++f)
                s[f] = __builtin_amdgcn_mfma_f32_16x16x32_f16(kf4[ks], fb[f][ks], s[f], 0, 0, 0);
        __builtin_amdgcn_s_setprio(0);

        // (c) wave-local max per query (rows j = wv*16 + lg*4 + r)
        float tm[4];
#pragma unroll
        for (int f = 0; f < 4; ++f) {
            float t0 = fmaxf(fmaxf(s[f][0], s[f][1]), fmaxf(s[f][2], s[f][3]));
            t0 = fmaxf(t0, __shfl_xor(t0, 16));
            t0 = fmaxf(t0, __shfl_xor(t0, 32));
            tm[f] = t0;
        }
        if (lane < 16) {
#pragma unroll
            for (int f = 0; f < 4; ++f) smax[wv][f][li] = tm[f];
        }
        // V prefetch for PV kf=0, issued before the barrier (latency hides under it)
        f16x8 va[2][4];
#pragma unroll
        for (int cf = 0; cf < 4; ++cf) va[0][cf] = *(const f16x8*)(vbase + (size_t)(cf * 16) * N + j0);
        __syncthreads();   // B1: max stats visible
        // (d) tile max over 8 waves (broadcast reads)
        float gm[4];
#pragma unroll
        for (int f = 0; f < 4; ++f) {
            float m0 = smax[0][f][li];
#pragma unroll
            for (int w = 1; w < 8; ++w) m0 = fmaxf(m0, smax[w][f][li]);
            gm[f] = m0;
        }
        // V prefetch for kf=1
#pragma unroll
        for (int cf = 0; cf < 4; ++cf) va[1][cf] = *(const f16x8*)(vbase + (size_t)(cf * 16) * N + j0 + 32);
        // T13 deferred rescale (identical decision in all waves: shared stats)
#pragma unroll
        for (int f = 0; f < 4; ++f) {
            if (!__all(gm[f] <= ms[f] + 8.0f)) {
                float mn = fmaxf(ms[f], gm[f]), sc = __expf(ms[f] - mn);
                ms[f] = mn; ls[f] *= sc;
#pragma unroll
                for (int cf = 0; cf < 4; ++cf) oacc[cf][f] *= sc;
            }
        }
        // exp (this wave's 4 j per lane per f) + P write + partial sums
        const int jl = wv * 16 + lg * 4;
        const int gg = (jl >> 3) ^ swl;
        float ps[4];
#pragma unroll
        for (int f = 0; f < 4; ++f) {
            f16x4 pk;
            float p0 = 0.f;
#pragma unroll
            for (int r = 0; r < 4; ++r) { float p = __expf(s[f][r] - ms[f]); p0 += p; pk[r] = (f16)p; }
            *(f16x4*)(&pbuf[(f * 16 + li) * 128 + gg * 8 + (jl & 7)]) = pk;
            ps[f] = p0;
        }
#pragma unroll
        for (int f = 0; f < 4; ++f) {
            ps[f] += __shfl_xor(ps[f], 16);
            ps[f] += __shfl_xor(ps[f], 32);
        }
        if (lane < 16) {
#pragma unroll
            for (int f = 0; f < 4; ++f) ssum[wv][f][li] = ps[f];
        }
        // write staged K tile to next buffer (loads from (a) drained by now)
#pragma unroll
        for (int k = 0; k < 4; ++k)
            *(f16x8*)(&kn[sr * 128 + ((sg + k) ^ ssw) * 8]) = stg[k];
        __syncthreads();   // B2: P + ssum + next-K visible
        // (f) accumulate l from shared partial sums
#pragma unroll
        for (int f = 0; f < 4; ++f) {
            float a0 = 0.f;
#pragma unroll
            for (int w = 0; w < 8; ++w) a0 += ssum[w][f][li];
            ls[f] += a0;
        }
        // (g) PV over full 128 j, this wave's 64 channels; rolling V prefetch
#pragma unroll
        for (int kf = 0; kf < 4; ++kf) {
            const int cur = kf & 1;
            const int g = (kf * 4 + lg) ^ swl;
            f16x8 pb[4];
#pragma unroll
            for (int f = 0; f < 4; ++f)
                pb[f] = *(const f16x8*)(&pbuf[(f * 16 + li) * 128 + g * 8]);
            f16x8 vv0 = va[cur][0], vv1 = va[cur][1], vv2 = va[cur][2], vv3 = va[cur][3];
            if (kf < 2) {
#pragma unroll
                for (int cf = 0; cf < 4; ++cf)
                    va[cur][cf] = *(const f16x8*)(vbase + (size_t)(cf * 16) * N + j0 + (kf + 2) * 32);
            }
            __builtin_amdgcn_s_setprio(1);
#pragma unroll
            for (int f = 0; f < 4; ++f) {
                oacc[0][f] = __builtin_amdgcn_mfma_f32_16x16x32_f16(vv0, pb[f], oacc[0][f], 0, 0, 0);
                oacc[1][f] = __builtin_amdgcn_mfma_f32_16x16x32_f16(vv1, pb[f], oacc[1][f], 0, 0, 0);
                oacc[2][f] = __builtin_amdgcn_mfma_f32_16x16x32_f16(vv2, pb[f], oacc[2][f], 0, 0, 0);
                oacc[3][f] = __builtin_amdgcn_mfma_f32_16x16x32_f16(vv3, pb[f], oacc[3][f], 0, 0, 0);
            }
            __builtin_amdgcn_s_setprio(0);
        }
        // no 3rd barrier: next iter's B1 orders pbuf/kbuf reuse
    }

    // epilogue: O[c][i], i coalesced over li; + residual
    const float alpha = alphap[0];
#pragma unroll
    for (int f = 0; f < 4; ++f) {
        const float invf = alpha / ls[f];
        const float* xp = x + (size_t)(b * C + c0) * N + i0 + f * 16 + li;
        float* op = out + (size_t)(b * C + c0) * N + i0 + f * 16 + li;
#pragma unroll
        for (int cf = 0; cf < 4; ++cf)
#pragma unroll
            for (int r = 0; r < 4; ++r) {
                const int cl = cf * 16 + lg * 4 + r;
                op[(size_t)cl * N] = oacc[cf][f][r] * invf + xp[(size_t)cl * N];
            }
    }
}

extern "C" void kernel_launch(void* const* d_in, const int* in_sizes, int n_in,
                              void* d_out, int out_size, void* d_ws, size_t ws_size,
                              hipStream_t stream) {
    const float* x     = (const float*)d_in[0];
    const float* Wf_w  = (const float*)d_in[1];
    const float* Wf_b  = (const float*)d_in[2];
    const float* Wh_w  = (const float*)d_in[3];
    const float* Wh_b  = (const float*)d_in[4];
    const float* Wl_w  = (const float*)d_in[5];
    const float* Wl_b  = (const float*)d_in[6];
    const float* alpha = (const float*)d_in[7];
    char* ws = (char*)d_ws;
    f16*   xt   = (f16*)(ws + WS_XT);
    f16*   fkb  = (f16*)(ws + WS_FK);
    f16*   vb   = (f16*)(ws + WS_V);
    f16*   wcat = (f16*)(ws + WS_WCAT);
    f16*   wl   = (f16*)(ws + WS_WL);
    float* bcat = (float*)(ws + WS_BC);
    float* out  = (float*)d_out;

    prep_weights<<<dim3((C * C + 255) / 256), dim3(256), 0, stream>>>(Wf_w, Wf_b, Wh_w, Wh_b, Wl_w, wcat, wl, bcat);
    transpose_x<<<dim3(BATCH * 8 * 64), dim3(256), 0, stream>>>(x, xt);
    proj_fk<<<dim3(256), dim3(256), 0, stream>>>(xt, wcat, bcat, fkb);
    proj_v<<<dim3(512), dim3(256), 0, stream>>>(xt, wl, Wl_b, vb);
    // 4 b x 64 query-tiles(64q) = 256 blocks x 8 waves = 1 block/CU, XCD-pinned
    attn<<<dim3(256), dim3(512), 0, stream>>>(fkb, vb, x, alpha, out);
}

// Round 12
// 188.289 us; speedup vs baseline: 1.7337x; 1.1785x over previous
//
#include <hip/hip_runtime.h>
#include <hip/hip_bf16.h>

typedef _Float16 f16;
typedef _Float16 f16x4 __attribute__((ext_vector_type(4)));
typedef _Float16 f16x8 __attribute__((ext_vector_type(8)));
typedef float f32x4 __attribute__((ext_vector_type(4)));

constexpr int BATCH = 4, C = 512, CQ = 128, N = 4096;
constexpr int FKD = 256; // f(128) + k(128) channels (conceptual; stored split below)

// workspace layout (bytes)
constexpr size_t WS_XT   = 0;                                      // f16 [B][N][C]        16 MB
constexpr size_t WS_FT   = WS_XT   + (size_t)BATCH * N * C * 2;    // f16 [B][N][128]       4 MB
constexpr size_t WS_KT   = WS_FT   + (size_t)BATCH * N * CQ * 2;   // f16 [B][N/4][4][128]  4 MB (tiled K)
constexpr size_t WS_V    = WS_KT   + (size_t)BATCH * N * CQ * 2;   // f16 [B][C/16][N/8][16][8] 16 MB (tiled V)
constexpr size_t WS_WCAT = WS_V    + (size_t)BATCH * C * N * 2;    // f16 [256][512]
constexpr size_t WS_WL   = WS_WCAT + (size_t)FKD * C * 2;          // f16 [512][512]
constexpr size_t WS_BC   = WS_WL   + (size_t)C * C * 2;            // f32 [256]

// ---------------------------------------------------------------- weights->fp16
__global__ void prep_weights(const float* __restrict__ Wf_w, const float* __restrict__ Wf_b,
                             const float* __restrict__ Wh_w, const float* __restrict__ Wh_b,
                             const float* __restrict__ Wl_w,
                             f16* __restrict__ wcat, f16* __restrict__ wl, float* __restrict__ bcat) {
    int i = blockIdx.x * 256 + threadIdx.x;                 // grid covers C*C
    if (i < FKD * C) {
        int o = i >> 9, c = i & 511;
        float v = (o < CQ) ? Wf_w[o * C + c] : Wh_w[(o - CQ) * C + c];
        wcat[i] = (f16)v;
    }
    if (i < C * C) wl[i] = (f16)Wl_w[i];
    if (i < FKD) bcat[i] = (i < CQ) ? Wf_b[i] : Wh_b[i - CQ];
}

// ---------------------------------------------------------------- x (B,C,N) f32 -> xT (B,N,C) f16
__global__ void transpose_x(const float* __restrict__ x, f16* __restrict__ xt) {
    __shared__ float tile[64][65];
    int gid = blockIdx.x;
    int b = gid >> 9, rem = gid & 511;
    int c0 = (rem >> 6) * 64, n0 = (rem & 63) * 64;
    int t = threadIdx.x;
    int tn = t & 63, tg = t >> 6;
    const float* xp = x + (size_t)b * C * N + (size_t)c0 * N + n0;
#pragma unroll
    for (int r = 0; r < 16; ++r) {
        int cl = tg + r * 4;
        tile[cl][tn] = xp[(size_t)cl * N + tn];
    }
    __syncthreads();
    f16* xo = xt + (size_t)b * N * C + (size_t)n0 * C + c0;
#pragma unroll
    for (int r = 0; r < 16; ++r) {
        int nl = tg + r * 4;
        xo[(size_t)nl * C + tn] = (f16)tile[tn][nl];
    }
}

// ---------------------------------------------------------------- FK projection (64n x 64o per wave)
// outputs: F half -> ft[b][n][o] (n-major, 128 wide); K half -> kt tiled
// kt[b][g][r][ck]: g = n>>2, r = n&3, ck = o-128  (4-row groups of 256B -> 1KB)
__global__ void __launch_bounds__(256) proj_fk(const f16* __restrict__ xt, const f16* __restrict__ wcat,
                                               const float* __restrict__ bcat,
                                               f16* __restrict__ ft, f16* __restrict__ kt) {
    int wid = blockIdx.x * 4 + (threadIdx.x >> 6);   // 1024 waves: b(2) nt(6) ot(2)
    int lane = threadIdx.x & 63;
    int li = lane & 15, lg = lane >> 4;
    int b  = wid >> 8;
    int nt = (wid >> 2) & 63;
    int ot = wid & 3;
    int n0 = nt * 64, o0 = ot * 64;
    const f16* ap = xt + (size_t)(b * N + n0 + li) * C + lg * 8;
    const f16* bp = wcat + (size_t)(o0 + li) * C + lg * 8;
    f32x4 acc[4][4] = {};
    for (int ks = 0; ks < 16; ++ks) {
        f16x8 a4[4], b4[4];
#pragma unroll
        for (int t = 0; t < 4; ++t) a4[t] = *(const f16x8*)(ap + (size_t)(t * 16) * C + ks * 32);
#pragma unroll
        for (int t = 0; t < 4; ++t) b4[t] = *(const f16x8*)(bp + (size_t)(t * 16) * C + ks * 32);
#pragma unroll
        for (int tA = 0; tA < 4; ++tA)
#pragma unroll
            for (int tB = 0; tB < 4; ++tB)
                acc[tA][tB] = __builtin_amdgcn_mfma_f32_16x16x32_f16(a4[tA], b4[tB], acc[tA][tB], 0, 0, 0);
    }
#pragma unroll
    for (int tB = 0; tB < 4; ++tB) {
        int o = o0 + tB * 16 + li;
        float bias = bcat[o];
        if (o < CQ) {
#pragma unroll
            for (int tA = 0; tA < 4; ++tA)
#pragma unroll
                for (int r = 0; r < 4; ++r) {
                    int n = n0 + tA * 16 + lg * 4 + r;
                    ft[((size_t)(b * N + n)) * CQ + o] = (f16)(acc[tA][tB][r] + bias);
                }
        } else {
            int ck = o - CQ;
#pragma unroll
            for (int tA = 0; tA < 4; ++tA)
#pragma unroll
                for (int r = 0; r < 4; ++r) {
                    int n = n0 + tA * 16 + lg * 4 + r;
                    kt[(((size_t)b * (N >> 2) + (n >> 2)) * 4 + (n & 3)) * 128 + ck] = (f16)(acc[tA][tB][r] + bias);
                }
        }
    }
}

// ---------------------------------------------------------------- V projection (64c x 64n per wave)
// output tiled: v[b][cp][jb][cl][jl]: cp=c>>4, cl=c&15, jb=n>>3, jl=n&7
__global__ void __launch_bounds__(256) proj_v(const f16* __restrict__ xt, const f16* __restrict__ wl,
                                              const float* __restrict__ wlb, f16* __restrict__ v) {
    int wid = blockIdx.x * 4 + (threadIdx.x >> 6);   // 2048 waves: b(2) ct(3) nt(6)
    int lane = threadIdx.x & 63;
    int li = lane & 15, lg = lane >> 4;
    int b  = wid >> 9;
    int ct = (wid >> 6) & 7;
    int nt = wid & 63;
    int c0 = ct * 64, n0 = nt * 64;
    const f16* ap = wl + (size_t)(c0 + li) * C + lg * 8;
    const f16* bp = xt + (size_t)(b * N + n0 + li) * C + lg * 8;
    f32x4 acc[4][4] = {};
    for (int ks = 0; ks < 16; ++ks) {
        f16x8 a4[4], b4[4];
#pragma unroll
        for (int t = 0; t < 4; ++t) a4[t] = *(const f16x8*)(ap + (size_t)(t * 16) * C + ks * 32);
#pragma unroll
        for (int t = 0; t < 4; ++t) b4[t] = *(const f16x8*)(bp + (size_t)(t * 16) * C + ks * 32);
#pragma unroll
        for (int tA = 0; tA < 4; ++tA)
#pragma unroll
            for (int tB = 0; tB < 4; ++tB)
                acc[tA][tB] = __builtin_amdgcn_mfma_f32_16x16x32_f16(a4[tA], b4[tB], acc[tA][tB], 0, 0, 0);
    }
#pragma unroll
    for (int tA = 0; tA < 4; ++tA)
#pragma unroll
        for (int r = 0; r < 4; ++r) {
            int c = c0 + tA * 16 + lg * 4 + r;
            float bias = wlb[c];
            const size_t cpb = ((size_t)b * 32 + (c >> 4)) * 512;
            const int cl = c & 15;
#pragma unroll
            for (int tB = 0; tB < 4; ++tB) {
                int n = n0 + tB * 16 + li;
                v[(cpb + (n >> 3)) * 128 + cl * 8 + (n & 7)] = (f16)(acc[tA][tB][r] + bias);
            }
        }
}

// ---------------------------------------------------------------- flash attention + residual (v12)
// v4 champion schedule verbatim (8 waves, 64q, KVBLK=128, reg-staged dbuf kbuf,
// shared-stats softmax, 2 barriers/iter, rolling V prefetch, XCD-pinned), with
// TILED operand layouts so every K-stage / V-fragment wave-load is 1KB contiguous:
//   K: kt[b][n/4][4][128] -> stage instr k reads rows wv*16+k*4+{0..3} = 1KB
//      (linear granule li from global; XOR applied on LDS write; reader unchanged)
//   V: v[b][cp][jb][16][8] -> fragment (16c x 32j) = 64 consecutive 16B chunks
__global__ void __launch_bounds__(512, 2) attn(const f16* __restrict__ ft, const f16* __restrict__ kt,
                                               const f16* __restrict__ v,
                                               const float* __restrict__ x, const float* __restrict__ alphap,
                                               float* __restrict__ out) {
    __shared__ __align__(16) f16 kbuf[2][128 * 128];   // 64 KB K tile, double-buffered
    __shared__ __align__(16) f16 pbuf[64 * 128];       // 16 KB shared P
    __shared__ float smax[8][4][16];
    __shared__ float ssum[8][4][16];

    const int tid  = threadIdx.x;
    const int wv   = tid >> 6;
    const int lane = tid & 63;
    const int li = lane & 15, lg = lane >> 4;
    const int swl = li & 7;
    // XCD-pinning: under blk%8 round-robin, each XCD sees a single batch
    const int v0 = blockIdx.x;
    const int b  = (v0 & 7) >> 1;
    const int it = ((v0 & 1) << 5) | (v0 >> 3);
    const int i0 = it * 64;
    const int c0 = wv * 64;

    // F fragments (B operand of swapped QK): col=i, k=ck; 4 i-frags
    f16x8 fb[4][4];
#pragma unroll
    for (int f = 0; f < 4; ++f) {
        const f16* fp = ft + (size_t)(b * N + i0 + f * 16 + li) * CQ + lg * 8;
#pragma unroll
        for (int ks = 0; ks < 4; ++ks) fb[f][ks] = *(const f16x8*)(fp + ks * 32);
    }

    // K staging from tiled kt: instr k covers rows wv*16 + k*4 + lg, granule li
    // (contiguous 1KB). LDS write applies XOR ^(row&7); QK reader uses swl as in v4.
    const f16* ktb = kt + (size_t)b * N * 128;
    {   // prologue: stage tile 0 -> kbuf[0]
#pragma unroll
        for (int k = 0; k < 4; ++k) {
            f16x8 vv = *(const f16x8*)(ktb + (((size_t)(wv * 4 + k)) * 4 + lg) * 128 + li * 8);
            *(f16x8*)(&kbuf[0][(wv * 16 + k * 4 + lg) * 128 + ((li ^ ((k * 4 + lg) & 7)) * 8)]) = vv;
        }
    }

    // tiled V base: fragment (cf, phase) at vb2 + (cf*512 + t*16 + ph*4)*128
    const f16* vb2 = v + (((size_t)b * 32 + wv * 4) * 512 + lg) * 128 + li * 8;
    f32x4 oacc[4][4] = {};                       // [c-frag][i-frag]
    float ms[4] = {-1e30f, -1e30f, -1e30f, -1e30f};
    float ls[4] = {0.f, 0.f, 0.f, 0.f};
    __syncthreads();

    for (int t = 0; t < 32; ++t) {
        const f16* kc = &kbuf[t & 1][0];
        f16*       kn = &kbuf[(t + 1) & 1][0];
        const size_t jb0 = (size_t)t * 16;
        // (a) issue next K-tile global loads early (T14 issue-early/write-late)
        const int gn = (t < 31) ? (t + 1) * 32 : 0;   // group base = tile*32
        f16x8 stg[4];
#pragma unroll
        for (int k = 0; k < 4; ++k)
            stg[k] = *(const f16x8*)(ktb + (((size_t)(gn + wv * 4 + k)) * 4 + lg) * 128 + li * 8);

        // (b) QK for this wave's 16-j slice, all 4 i-frags
        f16x8 kf4[4];
#pragma unroll
        for (int ks = 0; ks < 4; ++ks)
            kf4[ks] = *(const f16x8*)(&kc[(wv * 16 + li) * 128 + ((ks * 4 + lg) ^ swl) * 8]);
        f32x4 s[4] = {};
        __builtin_amdgcn_s_setprio(1);
#pragma unroll
        for (int ks = 0; ks < 4; ++ks)
#pragma unroll
            for (int f = 0; f < 4; ++f)
                s[f] = __builtin_amdgcn_mfma_f32_16x16x32_f16(kf4[ks], fb[f][ks], s[f], 0, 0, 0);
        __builtin_amdgcn_s_setprio(0);

        // (c) wave-local max per query (rows j = wv*16 + lg*4 + r)
        float tm[4];
#pragma unroll
        for (int f = 0; f < 4; ++f) {
            float t0 = fmaxf(fmaxf(s[f][0], s[f][1]), fmaxf(s[f][2], s[f][3]));
            t0 = fmaxf(t0, __shfl_xor(t0, 16));
            t0 = fmaxf(t0, __shfl_xor(t0, 32));
            tm[f] = t0;
        }
        if (lane < 16) {
#pragma unroll
            for (int f = 0; f < 4; ++f) smax[wv][f][li] = tm[f];
        }
        // V prefetch for PV kf=0, issued before the barrier (latency hides under it)
        f16x8 va[2][4];
#pragma unroll
        for (int cf = 0; cf < 4; ++cf) va[0][cf] = *(const f16x8*)(vb2 + ((size_t)cf * 512 + jb0) * 128);
        __syncthreads();   // B1: max stats visible
        // (d) tile max over 8 waves (broadcast reads)
        float gm[4];
#pragma unroll
        for (int f = 0; f < 4; ++f) {
            float m0 = smax[0][f][li];
#pragma unroll
            for (int w = 1; w < 8; ++w) m0 = fmaxf(m0, smax[w][f][li]);
            gm[f] = m0;
        }
        // V prefetch for kf=1
#pragma unroll
        for (int cf = 0; cf < 4; ++cf) va[1][cf] = *(const f16x8*)(vb2 + ((size_t)cf * 512 + jb0 + 4) * 128);
        // T13 deferred rescale (identical decision in all waves: shared stats)
#pragma unroll
        for (int f = 0; f < 4; ++f) {
            if (!__all(gm[f] <= ms[f] + 8.0f)) {
                float mn = fmaxf(ms[f], gm[f]), sc = __expf(ms[f] - mn);
                ms[f] = mn; ls[f] *= sc;
#pragma unroll
                for (int cf = 0; cf < 4; ++cf) oacc[cf][f] *= sc;
            }
        }
        // exp (this wave's 4 j per lane per f) + P write + partial sums
        const int jl = wv * 16 + lg * 4;
        const int gg = (jl >> 3) ^ swl;
        float ps[4];
#pragma unroll
        for (int f = 0; f < 4; ++f) {
            f16x4 pk;
            float p0 = 0.f;
#pragma unroll
            for (int r = 0; r < 4; ++r) { float p = __expf(s[f][r] - ms[f]); p0 += p; pk[r] = (f16)p; }
            *(f16x4*)(&pbuf[(f * 16 + li) * 128 + gg * 8 + (jl & 7)]) = pk;
            ps[f] = p0;
        }
#pragma unroll
        for (int f = 0; f < 4; ++f) {
            ps[f] += __shfl_xor(ps[f], 16);
            ps[f] += __shfl_xor(ps[f], 32);
        }
        if (lane < 16) {
#pragma unroll
            for (int f = 0; f < 4; ++f) ssum[wv][f][li] = ps[f];
        }
        // write staged K tile to next buffer (loads from (a) drained by now)
#pragma unroll
        for (int k = 0; k < 4; ++k)
            *(f16x8*)(&kn[(wv * 16 + k * 4 + lg) * 128 + ((li ^ ((k * 4 + lg) & 7)) * 8)]) = stg[k];
        __syncthreads();   // B2: P + ssum + next-K visible
        // (f) accumulate l from shared partial sums
#pragma unroll
        for (int f = 0; f < 4; ++f) {
            float a0 = 0.f;
#pragma unroll
            for (int w = 0; w < 8; ++w) a0 += ssum[w][f][li];
            ls[f] += a0;
        }
        // (g) PV over full 128 j, this wave's 64 channels; rolling V prefetch
#pragma unroll
        for (int kf = 0; kf < 4; ++kf) {
            const int cur = kf & 1;
            const int g = (kf * 4 + lg) ^ swl;
            f16x8 pb[4];
#pragma unroll
            for (int f = 0; f < 4; ++f)
                pb[f] = *(const f16x8*)(&pbuf[(f * 16 + li) * 128 + g * 8]);
            f16x8 vv0 = va[cur][0], vv1 = va[cur][1], vv2 = va[cur][2], vv3 = va[cur][3];
            if (kf < 2) {
#pragma unroll
                for (int cf = 0; cf < 4; ++cf)
                    va[cur][cf] = *(const f16x8*)(vb2 + ((size_t)cf * 512 + jb0 + (kf + 2) * 4) * 128);
            }
            __builtin_amdgcn_s_setprio(1);
#pragma unroll
            for (int f = 0; f < 4; ++f) {
                oacc[0][f] = __builtin_amdgcn_mfma_f32_16x16x32_f16(vv0, pb[f], oacc[0][f], 0, 0, 0);
                oacc[1][f] = __builtin_amdgcn_mfma_f32_16x16x32_f16(vv1, pb[f], oacc[1][f], 0, 0, 0);
                oacc[2][f] = __builtin_amdgcn_mfma_f32_16x16x32_f16(vv2, pb[f], oacc[2][f], 0, 0, 0);
                oacc[3][f] = __builtin_amdgcn_mfma_f32_16x16x32_f16(vv3, pb[f], oacc[3][f], 0, 0, 0);
            }
            __builtin_amdgcn_s_setprio(0);
        }
        // no 3rd barrier: next iter's B1 orders pbuf/kbuf reuse
    }

    // epilogue: O[c][i], i coalesced over li; + residual
    const float alpha = alphap[0];
#pragma unroll
    for (int f = 0; f < 4; ++f) {
        const float invf = alpha / ls[f];
        const float* xp = x + (size_t)(b * C + c0) * N + i0 + f * 16 + li;
        float* op = out + (size_t)(b * C + c0) * N + i0 + f * 16 + li;
#pragma unroll
        for (int cf = 0; cf < 4; ++cf)
#pragma unroll
            for (int r = 0; r < 4; ++r) {
                const int cl = cf * 16 + lg * 4 + r;
                op[(size_t)cl * N] = oacc[cf][f][r] * invf + xp[(size_t)cl * N];
            }
    }
}

extern "C" void kernel_launch(void* const* d_in, const int* in_sizes, int n_in,
                              void* d_out, int out_size, void* d_ws, size_t ws_size,
                              hipStream_t stream) {
    const float* x     = (const float*)d_in[0];
    const float* Wf_w  = (const float*)d_in[1];
    const float* Wf_b  = (const float*)d_in[2];
    const float* Wh_w  = (const float*)d_in[3];
    const float* Wh_b  = (const float*)d_in[4];
    const float* Wl_w  = (const float*)d_in[5];
    const float* Wl_b  = (const float*)d_in[6];
    const float* alpha = (const float*)d_in[7];
    char* ws = (char*)d_ws;
    f16*   xt   = (f16*)(ws + WS_XT);
    f16*   ftb  = (f16*)(ws + WS_FT);
    f16*   ktb  = (f16*)(ws + WS_KT);
    f16*   vb   = (f16*)(ws + WS_V);
    f16*   wcat = (f16*)(ws + WS_WCAT);
    f16*   wl   = (f16*)(ws + WS_WL);
    float* bcat = (float*)(ws + WS_BC);
    float* out  = (float*)d_out;

    prep_weights<<<dim3((C * C + 255) / 256), dim3(256), 0, stream>>>(Wf_w, Wf_b, Wh_w, Wh_b, Wl_w, wcat, wl, bcat);
    transpose_x<<<dim3(BATCH * 8 * 64), dim3(256), 0, stream>>>(x, xt);
    proj_fk<<<dim3(256), dim3(256), 0, stream>>>(xt, wcat, bcat, ftb, ktb);
    proj_v<<<dim3(512), dim3(256), 0, stream>>>(xt, wl, Wl_b, vb);
    // 4 b x 64 query-tiles(64q) = 256 blocks x 8 waves = 1 block/CU, XCD-pinned
    attn<<<dim3(256), dim3(512), 0, stream>>>(ftb, ktb, vb, x, alpha, out);
}